// Round 4
// baseline (269.799 us; speedup 1.0000x reference)
//
#include <hip/hip_runtime.h>

// loss = sum((input - target)^2) / (N/4), by orthonormality of the 2x2 Haar
// transform (sum of the 4 band MSEs == overall pixel SSE * 4/N).
// N = 4*32*512*512 = 33554432; divisor = N/4 = 8388608.
//
// Harness floor: ~170 us = d_ws 512MB fill (78us @6.9TB/s) + d_in restore
// (~90us). Controllable part = stage1 (+ tiny stage2), currently ~72us.
//
// R9 (this file): R8's 8-deep per-wave pipeline barely moved stage1 (75->72)
// -> per-wave depth is not the limiter at 16 waves/CU. The harness's own
// fast kernels (fill 6.9 TB/s @ 8 VGPR, restore copy) all run 8 waves/SIMD;
// every ~3.5 TB/s variant of ours ran 4 waves/SIMD. CDNA hides memory
// latency primarily via TLP -> double resident waves ~= double sustained
// in-flight bytes. Fix: depth-2 double buffer (32 data VGPRs) +
// __launch_bounds__(256, 8) to force VGPR<=64 -> 8 blocks/CU = 32 waves/CU,
// grid 2048 blocks. Keep nt loads (25% faster than plain in this regime,
// R6 A/B) and the sched_barrier'd prefetch->compute structure.
// Predicted: VGPR<=64, Occupancy ~100%, stage1 72 -> 45-55us, total
// ~225-232us. If neutral: limiter is restore-writeback HBM interference
// (environmental floor) -> reassess roofline.

typedef float fvec4 __attribute__((ext_vector_type(4)));

#define S1_BLOCK   256
#define S1_DEPTH   2                    // float4s per batch per thread per tensor
#define S1_BATCHES 8                    // batches per thread
#define S1_CHUNK   (S1_BLOCK * S1_DEPTH * S1_BATCHES)   // 4096 float4s per tensor per block

__global__ __launch_bounds__(S1_BLOCK, 8) void haar_mse_stage1(
    const fvec4* __restrict__ x,
    const fvec4* __restrict__ t,
    float* __restrict__ ws,
    int n4)
{
    const int tid  = threadIdx.x;
    const int base = blockIdx.x * S1_CHUNK + tid;

    float acc0 = 0.0f, acc1 = 0.0f, acc2 = 0.0f, acc3 = 0.0f;

    if (blockIdx.x * S1_CHUNK + S1_CHUNK <= n4) {
        // fast path (always taken for the bench shape):
        // depth-2 double-buffered prefetch; batch j+1's 4 nt loads are in
        // flight while batch j is consumed. Full unroll -> static indices.
        fvec4 a[2][S1_DEPTH], b[2][S1_DEPTH];

        // prologue: batch 0 into buffer 0
        #pragma unroll
        for (int k = 0; k < S1_DEPTH; ++k) {
            a[0][k] = __builtin_nontemporal_load(&x[base + k * S1_BLOCK]);
            b[0][k] = __builtin_nontemporal_load(&t[base + k * S1_BLOCK]);
        }

        #pragma unroll
        for (int j = 0; j < S1_BATCHES; ++j) {
            const int cur = j & 1;
            const int nxt = cur ^ 1;
            if (j + 1 < S1_BATCHES) {
                const int nb = base + (j + 1) * (S1_DEPTH * S1_BLOCK);
                #pragma unroll
                for (int k = 0; k < S1_DEPTH; ++k) {
                    a[nxt][k] = __builtin_nontemporal_load(&x[nb + k * S1_BLOCK]);
                    b[nxt][k] = __builtin_nontemporal_load(&t[nb + k * S1_BLOCK]);
                }
            }
            // keep the prefetch cluster above the compute (no sinking/hoisting)
            __builtin_amdgcn_sched_barrier(0);
            #pragma unroll
            for (int k = 0; k < S1_DEPTH; ++k) {
                fvec4 d = a[cur][k] - b[cur][k];
                acc0 = fmaf(d.x, d.x, acc0);
                acc1 = fmaf(d.y, d.y, acc1);
                acc2 = fmaf(d.z, d.z, acc2);
                acc3 = fmaf(d.w, d.w, acc3);
            }
        }
    } else {
        // tail path (not taken for the bench shape)
        for (int j = 0; j < S1_BATCHES; ++j) {
            for (int k = 0; k < S1_DEPTH; ++k) {
                const int i = base + j * (S1_DEPTH * S1_BLOCK) + k * S1_BLOCK;
                if (i < n4) {
                    fvec4 av = x[i];
                    fvec4 bv = t[i];
                    fvec4 d = av - bv;
                    acc0 = fmaf(d.x, d.x, acc0);
                    acc1 = fmaf(d.y, d.y, acc1);
                    acc2 = fmaf(d.z, d.z, acc2);
                    acc3 = fmaf(d.w, d.w, acc3);
                }
            }
        }
    }

    float acc = (acc0 + acc1) + (acc2 + acc3);

    // wave (64-lane) shuffle reduction
    #pragma unroll
    for (int off = 32; off > 0; off >>= 1)
        acc += __shfl_down(acc, off, 64);

    __shared__ float wave_sums[4];
    const int wave = tid >> 6;
    const int lane = tid & 63;
    if (lane == 0) wave_sums[wave] = acc;
    __syncthreads();

    if (tid == 0)
        ws[blockIdx.x] = (wave_sums[0] + wave_sums[1]) + (wave_sums[2] + wave_sums[3]);
}

__global__ __launch_bounds__(256) void haar_mse_stage2(
    const float* __restrict__ ws,
    float* __restrict__ out,
    int nblocks,
    float scale)
{
    float s = 0.0f;
    for (int i = threadIdx.x; i < nblocks; i += 256)
        s += ws[i];

    #pragma unroll
    for (int off = 32; off > 0; off >>= 1)
        s += __shfl_down(s, off, 64);

    __shared__ float wave_sums[4];
    const int wave = threadIdx.x >> 6;
    const int lane = threadIdx.x & 63;
    if (lane == 0) wave_sums[wave] = s;
    __syncthreads();

    if (threadIdx.x == 0)
        out[0] = ((wave_sums[0] + wave_sums[1]) + (wave_sums[2] + wave_sums[3])) * scale;
}

extern "C" void kernel_launch(void* const* d_in, const int* in_sizes, int n_in,
                              void* d_out, int out_size, void* d_ws, size_t ws_size,
                              hipStream_t stream) {
    const float* x = (const float*)d_in[0];
    const float* t = (const float*)d_in[1];
    float* out = (float*)d_out;
    float* ws  = (float*)d_ws;

    const int n  = in_sizes[0];   // 33554432
    const int n4 = n / 4;         // 8388608 float4s
    const int nblocks = (n4 + S1_CHUNK - 1) / S1_CHUNK;   // 2048

    haar_mse_stage1<<<nblocks, S1_BLOCK, 0, stream>>>(
        (const fvec4*)x, (const fvec4*)t, ws, n4);

    const float scale = 1.0f / (float)(n / 4);            // 1/8388608
    haar_mse_stage2<<<1, 256, 0, stream>>>(ws, out, nblocks, scale);
}